// Round 1
// baseline (196.802 us; speedup 1.0000x reference)
//
#include <hip/hip_runtime.h>

// Problem constants (from reference):
//   x:       [B=16, E=64, S=32768] float32
//   indices: [B=16, E=64] int (values in [0, S/STEP))
//   out:     [B, 1, S] float32  -> flat B*S
// out[b,s] = sum_e x[b, e, s - idx[b,e]*STEP]  where idx*STEP <= s
constexpr int B = 16;
constexpr int E = 64;
constexpr int S = 32768;
constexpr int STEP = 256;
constexpr int SAMPLES_PER_BLOCK = 1024;   // 256 threads * float4

__global__ __launch_bounds__(256)
void sparse_audio_gather(const float* __restrict__ x,
                         const int* __restrict__ idx,
                         float* __restrict__ out) {
    const int b  = blockIdx.y;
    const int s0 = blockIdx.x * SAMPLES_PER_BLOCK + threadIdx.x * 4;

    // Stage the 64 per-batch event offsets (block-uniform) in LDS.
    __shared__ int t_lds[E];
    if (threadIdx.x < E) {
        t_lds[threadIdx.x] = idx[b * E + threadIdx.x] * STEP;
    }
    __syncthreads();

    const float* xb = x + (size_t)b * E * S;

    float4 acc = make_float4(0.f, 0.f, 0.f, 0.f);
    // t_e is a multiple of STEP=256 and s0 a multiple of 4, so the whole
    // float4 is either fully in-range (s0 >= t_e) or fully out (s0 < t_e).
    #pragma unroll 8
    for (int e = 0; e < E; ++e) {
        const int te = t_lds[e];
        if (s0 >= te) {
            const float4 v =
                *reinterpret_cast<const float4*>(xb + (size_t)e * S + (s0 - te));
            acc.x += v.x;
            acc.y += v.y;
            acc.z += v.z;
            acc.w += v.w;
        }
    }

    *reinterpret_cast<float4*>(out + (size_t)b * S + s0) = acc;
}

extern "C" void kernel_launch(void* const* d_in, const int* in_sizes, int n_in,
                              void* d_out, int out_size, void* d_ws, size_t ws_size,
                              hipStream_t stream) {
    const float* x   = (const float*)d_in[0];
    const int*   idx = (const int*)d_in[1];
    float*       out = (float*)d_out;

    dim3 grid(S / SAMPLES_PER_BLOCK, B);  // (32, 16)
    dim3 block(256);
    sparse_audio_gather<<<grid, block, 0, stream>>>(x, idx, out);
}

// Round 2
// 175.774 us; speedup vs baseline: 1.1196x; 1.1196x over previous
//
#include <hip/hip_runtime.h>

// Problem constants (from reference):
//   x:       [B=16, E=64, S=32768] float32
//   indices: [B=16, E=64] int (values in [0, S/STEP))
//   out:     [B, 1, S] float32  -> flat B*S
// out[b,s] = sum_e x[b, e, s - idx[b,e]*STEP]  where idx*STEP <= s
constexpr int B = 16;
constexpr int E = 64;
constexpr int S = 32768;
constexpr int STEP = 256;
constexpr int SAMPLES_PER_BLOCK = 1024;   // 256 threads * float4
constexpr int GRP = 16;                   // loads in flight per thread

__global__ __launch_bounds__(256)
void sparse_audio_gather(const float* __restrict__ x,
                         const int* __restrict__ idx,
                         float* __restrict__ out) {
    const int b  = blockIdx.y;
    const int s0 = blockIdx.x * SAMPLES_PER_BLOCK + threadIdx.x * 4;

    // Stage the 64 per-batch event offsets (block-uniform) in LDS.
    __shared__ int t_lds[E];
    if (threadIdx.x < E) {
        t_lds[threadIdx.x] = idx[b * E + threadIdx.x] * STEP;
    }
    __syncthreads();

    const float* xb = x + (size_t)b * E * S;

    float4 acc = make_float4(0.f, 0.f, 0.f, 0.f);

    // Unconditional clamped loads (address max(s0-te,0) is always in-range),
    // masked after the fact. This lets the compiler issue GRP loads
    // back-to-back before any s_waitcnt -> 16 in-flight loads/thread instead
    // of one round-trip latency per event.
    for (int e0 = 0; e0 < E; e0 += GRP) {
        float4 v[GRP];
        float  m[GRP];
        #pragma unroll
        for (int j = 0; j < GRP; ++j) {
            const int off  = s0 - t_lds[e0 + j];
            const int offc = off < 0 ? 0 : off;       // clamped, always valid
            m[j] = off < 0 ? 0.0f : 1.0f;
            v[j] = *reinterpret_cast<const float4*>(
                       xb + (size_t)(e0 + j) * S + offc);
        }
        #pragma unroll
        for (int j = 0; j < GRP; ++j) {
            acc.x += m[j] * v[j].x;
            acc.y += m[j] * v[j].y;
            acc.z += m[j] * v[j].z;
            acc.w += m[j] * v[j].w;
        }
    }

    *reinterpret_cast<float4*>(out + (size_t)b * S + s0) = acc;
}

extern "C" void kernel_launch(void* const* d_in, const int* in_sizes, int n_in,
                              void* d_out, int out_size, void* d_ws, size_t ws_size,
                              hipStream_t stream) {
    const float* x   = (const float*)d_in[0];
    const int*   idx = (const int*)d_in[1];
    float*       out = (float*)d_out;

    dim3 grid(S / SAMPLES_PER_BLOCK, B);  // (32, 16)
    dim3 block(256);
    sparse_audio_gather<<<grid, block, 0, stream>>>(x, idx, out);
}